// Round 9
// baseline (260.345 us; speedup 1.0000x reference)
//
#include <hip/hip_runtime.h>

#define DEV __device__ __forceinline__
#define KSIG (-1.442695041f)
#define KTANH (-2.885390082f)

typedef float f2 __attribute__((ext_vector_type(2)));

DEV float fexp2(float x) { return __builtin_amdgcn_exp2f(x); }
DEV float frcp(float x) { return __builtin_amdgcn_rcpf(x); }
DEV f2 pkfma(f2 a, f2 b, f2 c) { return __builtin_elementwise_fma(a, b, c); }

// Broadcast lane (quad_base + S) to all 4 lanes of the quad via DPP quad_perm
// (VALU pipe -- zero DS traffic; this is the whole point of the quad scheme).
template <int S>
DEV float qb(float x) {
  int i = __builtin_amdgcn_update_dpp(0, __float_as_int(x), S * 0x55, 0xF, 0xF,
                                      true);
  return __int_as_float(i);
}

// Lane s of a quad owns gate rows 5s+j, j=0..4 (s: 0=i 1=f 2=g 3=o).
// kexp folded into weights/bias: sigmoid lanes scaled by KSIG, g-lane by
// KTANH, so act = m2*rcp(1+exp2(acc))+a2 with per-lane consts m2/a2.
struct CellQ {
  f2 wx01[5], wx23[5], wh01[5], wh23[5];
  float wx4[5], wh4[5], b[5];
};

DEV void load_cellQ(CellQ& W, int s, const float* __restrict__ Wih,
                    const float* __restrict__ Whh,
                    const float* __restrict__ bih,
                    const float* __restrict__ bhh) {
  const float kx = (s == 2) ? KTANH : KSIG;
#pragma unroll
  for (int j = 0; j < 5; ++j) {
    const int row = 5 * s + j;
    W.wx01[j] = (f2){kx * Wih[row * 5 + 0], kx * Wih[row * 5 + 1]};
    W.wx23[j] = (f2){kx * Wih[row * 5 + 2], kx * Wih[row * 5 + 3]};
    W.wx4[j] = kx * Wih[row * 5 + 4];
    W.wh01[j] = (f2){kx * Whh[row * 5 + 0], kx * Whh[row * 5 + 1]};
    W.wh23[j] = (f2){kx * Whh[row * 5 + 2], kx * Whh[row * 5 + 3]};
    W.wh4[j] = kx * Whh[row * 5 + 4];
    W.b[j] = kx * (bih[row] + bhh[row]);
  }
}

struct StateQ {
  f2 hp01, hp23;  // h0,h1 | h2,h3
  float h4;
  float c[5];
};

DEV void zeroQ(StateQ& st) {
  st.hp01 = (f2){0.f, 0.f};
  st.hp23 = (f2){0.f, 0.f};
  st.h4 = 0.f;
#pragma unroll
  for (int j = 0; j < 5; ++j) st.c[j] = 0.f;
}

// One cell timestep for 16 elements/wave. All 4 lanes of a quad redundantly
// update c/h (no cross-lane cost beyond 20 DPP broadcasts).
DEV void stepQ(const CellQ& W, f2 x01, f2 x23, float x4, StateQ& st, float m2,
               float a2) {
  float a[5];
#pragma unroll
  for (int j = 0; j < 5; ++j) {
    f2 acc2 = pkfma(W.wx01[j], x01, (f2){W.b[j], 0.f});
    acc2 = pkfma(W.wx23[j], x23, acc2);
    acc2 = pkfma(W.wh01[j], st.hp01, acc2);
    acc2 = pkfma(W.wh23[j], st.hp23, acc2);
    float acc = acc2.x + acc2.y;
    acc = fmaf(W.wx4[j], x4, acc);
    acc = fmaf(W.wh4[j], st.h4, acc);
    a[j] = fmaf(m2, frcp(1.f + fexp2(acc)), a2);
  }
#pragma unroll
  for (int j = 0; j < 5; ++j) {
    float I = qb<0>(a[j]);
    float F = qb<1>(a[j]);
    float G = qb<2>(a[j]);
    float O = qb<3>(a[j]);
    float cj = fmaf(F, st.c[j], I * G);
    st.c[j] = cj;
    float th = fmaf(2.f, frcp(1.f + fexp2(KTANH * cj)), -1.f);
    float h = O * th;
    if (j == 0)
      st.hp01.x = h;
    else if (j == 1)
      st.hp01.y = h;
    else if (j == 2)
      st.hp23.x = h;
    else if (j == 3)
      st.hp23.y = h;
    else
      st.h4 = h;
  }
}

// One wave per block; 16 elements (4 lanes each). 3 serial cells per thread
// ordered c2a -> c1 -> c2b so c1's independent work covers the c2a->c2b
// handoff chain. FC stack fused at the end. Zero DS ops in the recurrence.
__global__ __launch_bounds__(64, 1) void rnnq_kernel(
    const float* __restrict__ x1, const float* __restrict__ x2,
    const float* __restrict__ Wih1, const float* __restrict__ Whh1,
    const float* __restrict__ bih1, const float* __restrict__ bhh1,
    const float* __restrict__ Wih2a, const float* __restrict__ Whh2a,
    const float* __restrict__ bih2a, const float* __restrict__ bhh2a,
    const float* __restrict__ Wih2b, const float* __restrict__ Whh2b,
    const float* __restrict__ bih2b, const float* __restrict__ bhh2b,
    const float* __restrict__ W1, const float* __restrict__ b1,
    const float* __restrict__ W2, const float* __restrict__ b2,
    const float* __restrict__ W3, const float* __restrict__ b3,
    const float* __restrict__ W4, const float* __restrict__ b4,
    const float* __restrict__ W5, const float* __restrict__ b5,
    float* __restrict__ out, int B) {
  __shared__ float sIn[16][20];
  __shared__ float sA[16][32];
  __shared__ float sBf[16][32];

  const int l = threadIdx.x;
  const int e = l >> 2;
  const int s = l & 3;
  const int eg = blockIdx.x * 16 + e;
  const int egc = (eg < B) ? eg : (B - 1);

  CellQ Wc1, Wc2a, Wc2b;
  load_cellQ(Wc1, s, Wih1, Whh1, bih1, bhh1);
  load_cellQ(Wc2a, s, Wih2a, Whh2a, bih2a, bhh2a);
  load_cellQ(Wc2b, s, Wih2b, Whh2b, bih2b, bhh2b);

  const float m2 = (s == 2) ? 2.f : 1.f;
  const float a2 = (s == 2) ? -1.f : 0.f;

  const float* px1 = x1 + (size_t)egc * 640;
  const float* px2 = x2 + (size_t)egc * 640;

  StateQ s1, s2a, s2b;
  zeroQ(s1);
  zeroQ(s2a);
  zeroQ(s2b);

  f2 xa01 = (f2){px1[0], px1[1]}, xa23 = (f2){px1[2], px1[3]};
  float xa4 = px1[4];
  f2 xb01 = (f2){px2[0], px2[1]}, xb23 = (f2){px2[2], px2[3]};
  float xb4 = px2[4];

  for (int t = 0; t < 128; ++t) {
    const int tn = (t < 127) ? t + 1 : 127;
    // prefetch x(t+1) (uniform tn -> scalar select; loads fly during compute)
    f2 na01 = (f2){px1[tn * 5 + 0], px1[tn * 5 + 1]};
    f2 na23 = (f2){px1[tn * 5 + 2], px1[tn * 5 + 3]};
    float na4 = px1[tn * 5 + 4];
    f2 nb01 = (f2){px2[tn * 5 + 0], px2[tn * 5 + 1]};
    f2 nb23 = (f2){px2[tn * 5 + 2], px2[tn * 5 + 3]};
    float nb4 = px2[tn * 5 + 4];

    stepQ(Wc2a, xb01, xb23, xb4, s2a, m2, a2);
    stepQ(Wc1, xa01, xa23, xa4, s1, m2, a2);
    stepQ(Wc2b, s2a.hp01, s2a.hp23, s2a.h4, s2b, m2, a2);  // h2a(t) -> 2b

    xa01 = na01;
    xa23 = na23;
    xa4 = na4;
    xb01 = nb01;
    xb23 = nb23;
    xb4 = nb4;
  }

  // Stage FC inputs [x1_last, x2_last, h1, h2b]; quad lanes are redundant,
  // lane s==0 writes.
  if (s == 0) {
    sIn[e][0] = xa01.x;
    sIn[e][1] = xa01.y;
    sIn[e][2] = xa23.x;
    sIn[e][3] = xa23.y;
    sIn[e][4] = xa4;
    sIn[e][5] = xb01.x;
    sIn[e][6] = xb01.y;
    sIn[e][7] = xb23.x;
    sIn[e][8] = xb23.y;
    sIn[e][9] = xb4;
    sIn[e][10] = s1.hp01.x;
    sIn[e][11] = s1.hp01.y;
    sIn[e][12] = s1.hp23.x;
    sIn[e][13] = s1.hp23.y;
    sIn[e][14] = s1.h4;
    sIn[e][15] = s2b.hp01.x;
    sIn[e][16] = s2b.hp01.y;
    sIn[e][17] = s2b.hp23.x;
    sIn[e][18] = s2b.hp23.y;
    sIn[e][19] = s2b.h4;
  }
  __syncthreads();

  // FC stack: task-split over 64 lanes; n is loop-invariant per lane so the
  // weight-row loads hoist out of the e-loop (L1-resident anyway).
  {
    const int n = l & 31;
#pragma unroll
    for (int r = 0; r < 8; ++r) {
      int ei = (l >> 5) + 2 * r;
      float acc = b1[n];
#pragma unroll
      for (int k = 0; k < 20; ++k) acc = fmaf(W1[n * 20 + k], sIn[ei][k], acc);
      sA[ei][n] = fmaxf(acc, 0.f);
    }
  }
  __syncthreads();
  {
    const int n = l & 31;
#pragma unroll
    for (int r = 0; r < 8; ++r) {
      int ei = (l >> 5) + 2 * r;
      float acc = b2[n];
#pragma unroll
      for (int k = 0; k < 32; ++k) acc = fmaf(W2[n * 32 + k], sA[ei][k], acc);
      sBf[ei][n] = fmaxf(acc, 0.f);
    }
  }
  __syncthreads();
  {
    const int n = l & 15;
#pragma unroll
    for (int r = 0; r < 4; ++r) {
      int ei = (l >> 4) + 4 * r;
      float acc = b3[n];
#pragma unroll
      for (int k = 0; k < 32; ++k) acc = fmaf(W3[n * 32 + k], sBf[ei][k], acc);
      sA[ei][n] = fmaxf(acc, 0.f);  // reuse sA cols 0..15
    }
  }
  __syncthreads();
  {
    const int n = l & 15;
#pragma unroll
    for (int r = 0; r < 4; ++r) {
      int ei = (l >> 4) + 4 * r;
      float acc = b4[n];
#pragma unroll
      for (int k = 0; k < 16; ++k) acc = fmaf(W4[n * 16 + k], sA[ei][k], acc);
      sBf[ei][n] = fmaxf(acc, 0.f);
    }
  }
  __syncthreads();
#pragma unroll
  for (int r = 0; r < 2; ++r) {
    int task = l + 64 * r;
    if (task < 80) {
      int ei = task / 5, n = task - 5 * (task / 5);
      float acc = b5[n];
#pragma unroll
      for (int k = 0; k < 16; ++k) acc = fmaf(W5[n * 16 + k], sBf[ei][k], acc);
      int ego = blockIdx.x * 16 + ei;
      if (ego < B) out[(size_t)ego * 5 + n] = acc;
    }
  }
}

extern "C" void kernel_launch(void* const* d_in, const int* in_sizes, int n_in,
                              void* d_out, int out_size, void* d_ws,
                              size_t ws_size, hipStream_t stream) {
  const float* x1 = (const float*)d_in[0];
  const float* x2 = (const float*)d_in[1];
  const float* Wih1 = (const float*)d_in[2];
  const float* Whh1 = (const float*)d_in[3];
  const float* bih1 = (const float*)d_in[4];
  const float* bhh1 = (const float*)d_in[5];
  const float* Wih2a = (const float*)d_in[6];
  const float* Whh2a = (const float*)d_in[7];
  const float* bih2a = (const float*)d_in[8];
  const float* bhh2a = (const float*)d_in[9];
  const float* Wih2b = (const float*)d_in[10];
  const float* Whh2b = (const float*)d_in[11];
  const float* bih2b = (const float*)d_in[12];
  const float* bhh2b = (const float*)d_in[13];
  const float* W1 = (const float*)d_in[14];
  const float* b1 = (const float*)d_in[15];
  const float* W2 = (const float*)d_in[16];
  const float* b2 = (const float*)d_in[17];
  const float* W3 = (const float*)d_in[18];
  const float* b3 = (const float*)d_in[19];
  const float* W4 = (const float*)d_in[20];
  const float* b4 = (const float*)d_in[21];
  const float* W5 = (const float*)d_in[22];
  const float* b5 = (const float*)d_in[23];

  int B = in_sizes[0] / 640;  // [B,128,5]
  int nB = (B + 15) / 16;     // 16 elements per 64-thread block

  rnnq_kernel<<<nB, 64, 0, stream>>>(
      x1, x2, Wih1, Whh1, bih1, bhh1, Wih2a, Whh2a, bih2a, bhh2a, Wih2b, Whh2b,
      bih2b, bhh2b, W1, b1, W2, b2, W3, b3, W4, b4, W5, b5, (float*)d_out, B);
}